// Round 9
// baseline (76.475 us; speedup 1.0000x reference)
//
#include <hip/hip_runtime.h>
#include <math.h>

#define EP 65536
#define C 97
#define L 8
#define WAVES 4
#define ITERS 8                          // segments per wave
#define SEG_PER_BLOCK (WAVES * ITERS)    // 32
#define NBLOCKS (EP / SEG_PER_BLOCK)     // 2048 -> 8 blocks/CU exactly

// two / one independent butterfly sums, interleaved so cross-lane-op
// latencies overlap (6-level chains)
__device__ __forceinline__ void wsum2(float& a, float& b) {
#pragma unroll
    for (int o = 32; o > 0; o >>= 1) {
        a += __shfl_xor(a, o, 64);
        b += __shfl_xor(b, o, 64);
    }
}
__device__ __forceinline__ float wsum(float v) {
#pragma unroll
    for (int o = 32; o > 0; o >>= 1) v += __shfl_xor(v, o, 64);
    return v;
}

// One wave per segment-iteration, 8 iters/wave, register double-buffered
// prefetch. NO LDS staging: lane = column, segment-max is a pure
// in-register tree over 8 row loads (R8's staging cost 3x ds_write_b128 +
// 16x ds_read_b32 per iter ~ 58% LDS-pipe occupancy on top of the shuffle
// butterflies). Only 2 butterflies per iter (s_all, sp_pos); spos is
// linear -> deferred to a per-lane accumulator, reduced once at wave end.
// Labels pre-packed to bitmasks, eth readfirstlane'd to SGPRs (VGPR <= 64
// to hold the 8-waves/SIMD occupancy tier, enforced by launch_bounds).
// No device-scope fences/atomics (R4/R5 lesson: agent-scope release per
// block = per-block L2 writeback/inv = 4.5x regression).
__global__ __launch_bounds__(256, 8) void atloss_main(
        const float* __restrict__ logits,
        const float* __restrict__ labels,
        const int*   __restrict__ pos,
        float*       __restrict__ partials) {
    const int tid  = threadIdx.x;
    const int w    = tid >> 6;
    const int lane = tid & 63;
    const int jbase = blockIdx.x * SEG_PER_BLOCK + w * ITERS;

    __shared__ float s_loss[WAVES];

    const int  c0   = lane;
    const int  c1   = lane + 64;
    const bool has1 = (c1 < C);                   // 97 = 64 + 33

    // span starts -> SGPRs
    int st_l = 0;
    if (lane < ITERS) st_l = pos[2 * (jbase + lane)];
    int st_s[ITERS];
#pragma unroll
    for (int k = 0; k < ITERS; ++k)
        st_s[k] = __builtin_amdgcn_readlane(st_l, k);

    // positive-label bitmasks for all 8 segments (2 bits/lane/segment);
    // labels[:,0] forced to 0 per reference (lane>0 condition)
    unsigned pm0 = 0, pm1 = 0;
#pragma unroll
    for (int k = 0; k < ITERS; ++k) {
        const size_t lb = (size_t)(jbase + k) * C;
        const float l0 = __builtin_nontemporal_load(labels + lb + c0);
        const float l1 = has1 ? __builtin_nontemporal_load(labels + lb + c1)
                              : 0.0f;
        pm0 |= (unsigned)((lane > 0) && (l0 > 0.5f)) << k;
        pm1 |= (unsigned)(has1 && (l1 > 0.5f)) << k;
    }

    // raw threshold logits (wave-uniform) -> SGPRs
    float eth_s[ITERS];
#pragma unroll
    for (int k = 0; k < ITERS; ++k)
        eth_s[k] = __int_as_float(__builtin_amdgcn_readfirstlane(
            __float_as_int(logits[(size_t)(jbase + k) * C])));

    // ---- prefetch iteration 0: 8 rows x 2 column slots, lane = column ----
    float a0[L], a1[L];
    {
        const float* rb = logits + (size_t)st_s[0] * C;
#pragma unroll
        for (int r = 0; r < L; ++r) {
            a0[r] = __builtin_nontemporal_load(rb + r * C + c0);
            a1[r] = has1 ? __builtin_nontemporal_load(rb + r * C + c1)
                         : -INFINITY;
        }
    }

    float acc_uni = 0.0f, acc_spos = 0.0f;

#pragma unroll
    for (int it = 0; it < ITERS; ++it) {
        float v0[L], v1[L];
#pragma unroll
        for (int r = 0; r < L; ++r) { v0[r] = a0[r]; v1[r] = a1[r]; }
        if (it + 1 < ITERS) {
            const float* rb = logits + (size_t)st_s[it + 1] * C;
#pragma unroll
            for (int r = 0; r < L; ++r) {
                a0[r] = __builtin_nontemporal_load(rb + r * C + c0);
                a1[r] = has1 ? __builtin_nontemporal_load(rb + r * C + c1)
                             : -INFINITY;
            }
        }
        const float eth = eth_s[it];

        // in-register segment max (tree)
        float e0 = fmaxf(fmaxf(fmaxf(v0[0], v0[1]), fmaxf(v0[2], v0[3])),
                         fmaxf(fmaxf(v0[4], v0[5]), fmaxf(v0[6], v0[7])));
        float e1 = fmaxf(fmaxf(fmaxf(v1[0], v1[1]), fmaxf(v1[2], v1[3])),
                         fmaxf(fmaxf(v1[4], v1[5]), fmaxf(v1[6], v1[7])));
        if (lane == 0) e0 = eth;                  // e[0] = raw logits[j,0]

        const bool p0 = (pm0 >> it) & 1u;
        const bool p1 = (pm1 >> it) & 1u;
        const float npos = (float)(__popcll(__ballot(p0)) +
                                   __popcll(__ballot(p1)));

        const float x0 = __expf(e0);              // lane0: exp(eth)
        const float x1 = has1 ? __expf(e1) : 0.0f;

        float s_all  = x0 + x1;                               // all classes
        float sp_pos = (p0 ? x0 : 0.0f) + (p1 ? x1 : 0.0f);   // exp, positives
        wsum2(s_all, sp_pos);

        const float sp = __expf(eth) + sp_pos;    // p-set = {0} U positives
        const float sn = s_all - sp_pos;          // n-set = all \ positives
        acc_uni  += npos * __logf(sp) + (__logf(sn) - eth);   // uniform terms
        acc_spos += (p0 ? e0 : 0.0f) + (p1 ? e1 : 0.0f);      // linear, defer
    }

    const float wloss = acc_uni - wsum(acc_spos);

    if (lane == 0) s_loss[w] = wloss;
    __syncthreads();
    if (tid == 0) {
        partials[blockIdx.x] = s_loss[0] + s_loss[1] + s_loss[2] + s_loss[3];
    }
}

__global__ __launch_bounds__(256) void atloss_reduce(
        const float* __restrict__ partials, int n, float* __restrict__ out) {
    __shared__ double sh[256];
    double acc = 0.0;
    for (int i = threadIdx.x; i < n; i += 256) acc += (double)partials[i];
    sh[threadIdx.x] = acc;
    __syncthreads();
    for (int s = 128; s > 0; s >>= 1) {
        if (threadIdx.x < s) sh[threadIdx.x] += sh[threadIdx.x + s];
        __syncthreads();
    }
    if (threadIdx.x == 0) out[0] = (float)(sh[0] / (double)EP);
}

extern "C" void kernel_launch(void* const* d_in, const int* in_sizes, int n_in,
                              void* d_out, int out_size, void* d_ws, size_t ws_size,
                              hipStream_t stream) {
    const float* logits = (const float*)d_in[0];
    const float* labels = (const float*)d_in[1];
    const int*   pos    = (const int*)d_in[2];
    float* out      = (float*)d_out;
    float* partials = (float*)d_ws;   // 2048 floats = 8 KiB scratch

    atloss_main<<<NBLOCKS, 256, 0, stream>>>(logits, labels, pos, partials);
    atloss_reduce<<<1, 256, 0, stream>>>(partials, NBLOCKS, out);
}

// Round 10
// 46.580 us; speedup vs baseline: 1.6418x; 1.6418x over previous
//
#include <hip/hip_runtime.h>
#include <math.h>

#define EP 65536
#define C 97
#define L 8
#define WAVES 4
#define ITERS 8                          // segments per wave
#define SEG_PER_BLOCK (WAVES * ITERS)    // 32
#define NBLOCKS (EP / SEG_PER_BLOCK)     // 2048 -> 8 blocks/CU exactly
#define SEG_FLOATS (L * C)               // 776 floats, contiguous, 16B-aligned

typedef float f4 __attribute__((ext_vector_type(4)));

// one DPP add step: v += dpp_perm(v); runs on the VALU pipe (not LDS)
template <int CTRL, int RMASK>
__device__ __forceinline__ float dpp_step(float v) {
    return v + __int_as_float(__builtin_amdgcn_update_dpp(
                   0, __float_as_int(v), CTRL, RMASK, 0xf, true));
}

// wave-64 sum of two values via DPP (rocPRIM pattern), interleaved so the
// two dependency chains overlap. row_ror:8/4/2/1 -> every lane holds its
// 16-lane row sum; row_bcast15 (rows 1,3) + row_bcast31 (rows 2,3) fold
// rows so lane 63 holds the wave total; readlane 63 -> wave-uniform.
__device__ __forceinline__ void dpp_wsum2(float& a, float& b) {
    a = dpp_step<0x128, 0xf>(a); b = dpp_step<0x128, 0xf>(b);  // row_ror:8
    a = dpp_step<0x124, 0xf>(a); b = dpp_step<0x124, 0xf>(b);  // row_ror:4
    a = dpp_step<0x122, 0xf>(a); b = dpp_step<0x122, 0xf>(b);  // row_ror:2
    a = dpp_step<0x121, 0xf>(a); b = dpp_step<0x121, 0xf>(b);  // row_ror:1
    a = dpp_step<0x142, 0xa>(a); b = dpp_step<0x142, 0xa>(b);  // row_bcast15
    a = dpp_step<0x143, 0xc>(a); b = dpp_step<0x143, 0xc>(b);  // row_bcast31
    a = __int_as_float(__builtin_amdgcn_readlane(__float_as_int(a), 63));
    b = __int_as_float(__builtin_amdgcn_readlane(__float_as_int(b), 63));
}
__device__ __forceinline__ float dpp_wsum(float v) {
    v = dpp_step<0x128, 0xf>(v);
    v = dpp_step<0x124, 0xf>(v);
    v = dpp_step<0x122, 0xf>(v);
    v = dpp_step<0x121, 0xf>(v);
    v = dpp_step<0x142, 0xa>(v);
    v = dpp_step<0x143, 0xc>(v);
    return __int_as_float(__builtin_amdgcn_readlane(__float_as_int(v), 63));
}

// R8 skeleton (float4->LDS staging, register double-buffered prefetch,
// wave-private LDS slice, no fences/atomics) with the cross-lane work
// moved off the LDS pipe: 2 DPP reductions/iter (s_all, sp_pos) on the
// VALU pipe, spos (linear) deferred to ONE end-of-wave reduction.
// R9 lesson: keep the float4 staging -- 16 scalar loads/iter quadruples
// VMEM instruction count and regresses 1.6x.
__global__ __launch_bounds__(256) void atloss_main(
        const float* __restrict__ logits,
        const float* __restrict__ labels,
        const int*   __restrict__ pos,
        float*       __restrict__ partials) {
    const int tid  = threadIdx.x;
    const int w    = tid >> 6;
    const int lane = tid & 63;
    const int jbase = blockIdx.x * SEG_PER_BLOCK + w * ITERS;

    __shared__ float s_log[WAVES * SEG_FLOATS];   // 12416 B
    __shared__ float s_loss[WAVES];
    float* seg_s = s_log + w * SEG_FLOATS;        // wave-private slice
    f4*    s4    = (f4*)seg_s;                    // 3104 % 16 == 0

    const int  c0   = lane;
    const int  c1   = lane + 64;
    const bool has1 = (c1 < C);                   // 97 = 64 + 33

    int st_l = 0;
    if (lane < ITERS) st_l = pos[2 * (jbase + lane)];
    int st_s[ITERS];
#pragma unroll
    for (int k = 0; k < ITERS; ++k)
        st_s[k] = __builtin_amdgcn_readlane(st_l, k);

    // ---- prefetch iteration 0 ----
    const f4* g4 = (const f4*)(logits + (size_t)st_s[0] * C);
    f4 A0 = __builtin_nontemporal_load(g4 + lane);
    f4 A1 = __builtin_nontemporal_load(g4 + lane + 64);
    f4 A2 = __builtin_nontemporal_load(g4 + lane + 128);
    f4 A3 = (f4){0.f, 0.f, 0.f, 0.f};
    if (lane < 2) A3 = __builtin_nontemporal_load(g4 + 192 + lane);
    const size_t lbb = (size_t)jbase * C;
    float LB0 = __builtin_nontemporal_load(labels + lbb + c0);
    float LB1 = has1 ? __builtin_nontemporal_load(labels + lbb + c1) : 0.0f;
    float ETH = logits[(size_t)jbase * C];        // raw threshold logit

    float acc_uni = 0.0f, acc_spos = 0.0f;

#pragma unroll
    for (int it = 0; it < ITERS; ++it) {
        const f4 B0 = A0, B1 = A1, B2 = A2, B3 = A3;
        const float lb0 = LB0, lb1 = LB1, eth = ETH;
        if (it + 1 < ITERS) {
            const int j1 = jbase + it + 1;
            const f4* g4n = (const f4*)(logits + (size_t)st_s[it + 1] * C);
            A0 = __builtin_nontemporal_load(g4n + lane);
            A1 = __builtin_nontemporal_load(g4n + lane + 64);
            A2 = __builtin_nontemporal_load(g4n + lane + 128);
            if (lane < 2) A3 = __builtin_nontemporal_load(g4n + 192 + lane);
            const size_t lbn = (size_t)j1 * C;
            LB0 = __builtin_nontemporal_load(labels + lbn + c0);
            LB1 = has1 ? __builtin_nontemporal_load(labels + lbn + c1) : 0.0f;
            ETH = logits[(size_t)j1 * C];
        }

        // stage current segment into the wave-private LDS slice
        s4[lane] = B0; s4[lane + 64] = B1; s4[lane + 128] = B2;
        if (lane < 2) s4[192 + lane] = B3;

        // per-class segment max from LDS (tree; lane-consecutive = 2-way free)
        float e0, e1 = -INFINITY;
        {
            const float m01 = fmaxf(seg_s[0 * C + c0], seg_s[1 * C + c0]);
            const float m23 = fmaxf(seg_s[2 * C + c0], seg_s[3 * C + c0]);
            const float m45 = fmaxf(seg_s[4 * C + c0], seg_s[5 * C + c0]);
            const float m67 = fmaxf(seg_s[6 * C + c0], seg_s[7 * C + c0]);
            e0 = fmaxf(fmaxf(m01, m23), fmaxf(m45, m67));
        }
        if (has1) {
            const float m01 = fmaxf(seg_s[0 * C + c1], seg_s[1 * C + c1]);
            const float m23 = fmaxf(seg_s[2 * C + c1], seg_s[3 * C + c1]);
            const float m45 = fmaxf(seg_s[4 * C + c1], seg_s[5 * C + c1]);
            const float m67 = fmaxf(seg_s[6 * C + c1], seg_s[7 * C + c1]);
            e1 = fmaxf(fmaxf(m01, m23), fmaxf(m45, m67));
        }
        if (lane == 0) e0 = eth;                  // e[0] = raw logits[j,0]

        const bool p0 = (lane > 0) && (lb0 > 0.5f);   // labels[:,0]=0 forced
        const bool p1 = has1 && (lb1 > 0.5f);
        const float npos = (float)(__popcll(__ballot(p0)) +
                                   __popcll(__ballot(p1)));

        const float x0 = __expf(e0);              // lane0: exp(eth)
        const float x1 = has1 ? __expf(e1) : 0.0f;

        float s_all  = x0 + x1;                               // all classes
        float sp_pos = (p0 ? x0 : 0.0f) + (p1 ? x1 : 0.0f);   // exp, positives
        dpp_wsum2(s_all, sp_pos);                 // VALU-pipe reductions

        const float sp = __expf(eth) + sp_pos;    // p-set = {0} U positives
        const float sn = s_all - sp_pos;          // n-set = all \ positives
        acc_uni  += npos * __logf(sp) + (__logf(sn) - eth);
        acc_spos += (p0 ? e0 : 0.0f) + (p1 ? e1 : 0.0f);      // linear, defer
    }

    const float wloss = acc_uni - dpp_wsum(acc_spos);

    if (lane == 0) s_loss[w] = wloss;
    __syncthreads();
    if (tid == 0) {
        partials[blockIdx.x] = s_loss[0] + s_loss[1] + s_loss[2] + s_loss[3];
    }
}

__global__ __launch_bounds__(256) void atloss_reduce(
        const float* __restrict__ partials, int n, float* __restrict__ out) {
    __shared__ double sh[256];
    double acc = 0.0;
    for (int i = threadIdx.x; i < n; i += 256) acc += (double)partials[i];
    sh[threadIdx.x] = acc;
    __syncthreads();
    for (int s = 128; s > 0; s >>= 1) {
        if (threadIdx.x < s) sh[threadIdx.x] += sh[threadIdx.x + s];
        __syncthreads();
    }
    if (threadIdx.x == 0) out[0] = (float)(sh[0] / (double)EP);
}

extern "C" void kernel_launch(void* const* d_in, const int* in_sizes, int n_in,
                              void* d_out, int out_size, void* d_ws, size_t ws_size,
                              hipStream_t stream) {
    const float* logits = (const float*)d_in[0];
    const float* labels = (const float*)d_in[1];
    const int*   pos    = (const int*)d_in[2];
    float* out      = (float*)d_out;
    float* partials = (float*)d_ws;   // 2048 floats = 8 KiB scratch

    atloss_main<<<NBLOCKS, 256, 0, stream>>>(logits, labels, pos, partials);
    atloss_reduce<<<1, 256, 0, stream>>>(partials, NBLOCKS, out);
}